// Round 3
// baseline (393.240 us; speedup 1.0000x reference)
//
#include <hip/hip_runtime.h>
#include <hip/hip_cooperative_groups.h>
#include <hip/hip_bf16.h>
#include <cstddef>

namespace cg = cooperative_groups;

#define T_TOK 1024
#define D_DIM 1024
#define H_DIM 512
#define E_EXP 8
#define P_CAP 2560          // max padded pairs @64-align: 2048 + 8*63 = 2552 -> 2560
#define MAX_MT 40           // 64-row m-tiles
#define LDA 72              // shorts per LDS row: 64 data + 8 pad
#define NK1 16              // gemm1 K-steps: 1024/64
#define NK2 8               // gemm2 K-steps: 512/64
#define GRID_B 512          // cooperative grid: 2 blocks/CU x 256 CU

typedef __attribute__((ext_vector_type(4)))  float    float4_t;
typedef __attribute__((ext_vector_type(16))) float    f32x16;
typedef __attribute__((ext_vector_type(8)))  short    short8_t;
typedef __attribute__((ext_vector_type(4)))  unsigned uint4_t;
typedef __attribute__((ext_vector_type(2)))  unsigned uint2_t;

__device__ __forceinline__ short f2bf(float f) {
  union { float f; unsigned u; } v; v.f = f;
  unsigned u = v.u;
  u += 0x7FFFu + ((u >> 16) & 1u);
  return (short)(u >> 16);
}

__device__ __forceinline__ unsigned pkbf(float a, float b) {
  union { __hip_bfloat162 h; unsigned u; } v;
  v.h = __float22bfloat162_rn(make_float2(a, b));
  return v.u;
}

union SharedU {
  float tt[64 * 69];                                   // 17.7 KB transpose tile
  struct { short A[2][64 * LDA], B1[2][64 * LDA], B3[2][64 * LDA]; } g1;  // 55.3 KB
  struct { short A[2][64 * LDA], B[2][128 * LDA]; } g2;                   // 55.3 KB
};

// ---- 64x64 fp32->bf16 transpose tile worker (stride-69 LDS, <=2-way) ----
__device__ __forceinline__ void transpose_tile(
    const float* __restrict__ src, short* __restrict__ dst, int N, int ldd,
    int row_off, int k0, int n0, int tid, float* tt) {
  const int kr = tid >> 4, nc = (tid & 15) * 4;
  #pragma unroll
  for (int p = 0; p < 4; ++p) {
    int k = p * 16 + kr;
    float4_t v = *(const float4_t*)(src + (size_t)(k0 + k) * N + n0 + nc);
    tt[k * 69 + nc]     = v[0];
    tt[k * 69 + nc + 1] = v[1];
    tt[k * 69 + nc + 2] = v[2];
    tt[k * 69 + nc + 3] = v[3];
  }
  __syncthreads();
  const int r8 = tid >> 3, c8 = tid & 7;
  #pragma unroll
  for (int p = 0; p < 2; ++p) {
    int row = p * 32 + r8;
    uint4_t u;
    #pragma unroll
    for (int jj = 0; jj < 4; ++jj)
      u[jj] = pkbf(tt[(c8 * 8 + 2 * jj) * 69 + row], tt[(c8 * 8 + 2 * jj + 1) * 69 + row]);
    *(uint4_t*)(dst + (size_t)(row_off + n0 + row) * ldd + k0 + c8 * 8) = u;
  }
  __syncthreads();                                     // protect tt before next unit
}

// ---- router: 4 tokens (one wave each) ----
__device__ __forceinline__ void router4(
    int u, const float* __restrict__ x, const float* __restrict__ gw,
    int* __restrict__ idx2, float* __restrict__ scale2, int tid) {
  const int wid = tid >> 6, lane = tid & 63;
  const int t = u * 4 + wid;
  const float* xr = x + (size_t)t * D_DIM;
  float acc[E_EXP];
  #pragma unroll
  for (int e = 0; e < E_EXP; ++e) acc[e] = 0.f;
  for (int d = lane; d < D_DIM; d += 64) {
    float xv = xr[d];
    float4_t g0 = *(const float4_t*)(gw + d * E_EXP);
    float4_t g1 = *(const float4_t*)(gw + d * E_EXP + 4);
    acc[0] += xv * g0[0]; acc[1] += xv * g0[1];
    acc[2] += xv * g0[2]; acc[3] += xv * g0[3];
    acc[4] += xv * g1[0]; acc[5] += xv * g1[1];
    acc[6] += xv * g1[2]; acc[7] += xv * g1[3];
  }
  #pragma unroll
  for (int off = 32; off >= 1; off >>= 1) {
    #pragma unroll
    for (int e = 0; e < E_EXP; ++e) acc[e] += __shfl_down(acc[e], off, 64);
  }
  if (lane == 0) {
    float m = acc[0];
    #pragma unroll
    for (int e = 1; e < E_EXP; ++e) m = fmaxf(m, acc[e]);
    float p[E_EXP]; float s = 0.f;
    #pragma unroll
    for (int e = 0; e < E_EXP; ++e) { p[e] = __expf(acc[e] - m); s += p[e]; }
    float inv = 1.f / s;
    #pragma unroll
    for (int e = 0; e < E_EXP; ++e) p[e] *= inv;
    int i1 = 0;
    #pragma unroll
    for (int e = 1; e < E_EXP; ++e) if (p[e] > p[i1]) i1 = e;  // low-index tiebreak
    int i2 = (i1 == 0) ? 1 : 0;
    #pragma unroll
    for (int e = 0; e < E_EXP; ++e) {
      if (e == i1 || e == i2) continue;
      if (p[e] > p[i2]) i2 = e;
    }
    idx2[2 * t]     = i1;  scale2[2 * t]     = p[i1];
    idx2[2 * t + 1] = i2;  scale2[2 * t + 1] = p[i2];
  }
}

// ================= fused cooperative kernel: 5 phases =================
__global__ __launch_bounds__(256, 2) void moe_fused(
    const float* __restrict__ x, const float* __restrict__ gw,
    const float* __restrict__ w1, const float* __restrict__ w2,
    const float* __restrict__ w3, short* __restrict__ w13t,
    short* __restrict__ w2t, int* __restrict__ idx2,
    float* __restrict__ scale2, int* __restrict__ ptok,
    float* __restrict__ pscale, int* __restrict__ meta,
    short* __restrict__ Ag, short* __restrict__ h,
    float* __restrict__ out) {
  cg::grid_group grid = cg::this_grid();
  __shared__ SharedU sh;
  __shared__ int s_cnt[E_EXP], s_base[E_EXP], s_cur[E_EXP];
  const int tid = threadIdx.x;
  const int bid = blockIdx.x;

  // ---- P0: transposes + router + out-zero + pair-init (3594 work units)
  for (int u = bid; u < 3594; u += GRID_B) {
    if (u < 2048) {                        // w13: 16 z * (16 ktile x 8 ntile)
      int z = u >> 7, rem = u & 127;
      int kt = rem & 15, nt = rem >> 4;
      int which = z >> 3, e = z & 7;
      const float* src = (which ? w3 : w1) + (size_t)e * D_DIM * H_DIM;
      short* dst = w13t + (size_t)e * D_DIM * (2 * H_DIM);
      transpose_tile(src, dst, H_DIM, D_DIM, which ? H_DIM : 0,
                     kt * 64, nt * 64, tid, sh.tt);
    } else if (u < 3072) {                 // w2: 8 e * (8 ktile x 16 ntile)
      int v = u - 2048;
      int e = v >> 7, rem = v & 127;
      int kt = rem & 7, nt = rem >> 3;
      const float* src = w2 + (size_t)e * H_DIM * D_DIM;
      short* dst = w2t + (size_t)e * D_DIM * H_DIM;
      transpose_tile(src, dst, D_DIM, H_DIM, 0, kt * 64, nt * 64, tid, sh.tt);
    } else if (u < 3328) {                 // router: 256 units x 4 tokens
      router4(u - 3072, x, gw, idx2, scale2, tid);
    } else if (u < 3584) {                 // out zero: 256 units x 16 KB
      int v = u - 3328;
      float4_t z4 = {0.f, 0.f, 0.f, 0.f};
      float4_t* o = (float4_t*)(out + (size_t)v * 4096);
      #pragma unroll
      for (int i = 0; i < 4; ++i) o[i * 256 + tid] = z4;
    } else {                               // pair-init: 10 units x 256 rows
      int p = (u - 3584) * 256 + tid;
      if (p < P_CAP) { ptok[p] = -1; pscale[p] = 0.f; }
    }
  }
  grid.sync();

  // ---- P1: scan (block 0 only): histogram -> 64-aligned bases -> assign
  if (bid == 0) {
    if (tid < E_EXP) { s_cnt[tid] = 0; s_cur[tid] = 0; }
    __syncthreads();
    for (int t = tid; t < T_TOK; t += 256) {
      atomicAdd(&s_cnt[idx2[2 * t]], 1);
      atomicAdd(&s_cnt[idx2[2 * t + 1]], 1);
    }
    __syncthreads();
    if (tid == 0) {
      int b = 0, g = 0;
      for (int e = 0; e < E_EXP; ++e) {
        s_base[e] = b;
        int al = (s_cnt[e] + 63) & ~63;    // 64-row tiles
        for (int j = 0; j < al; j += 64) { meta[1 + g] = e; meta[81 + g] = b + j; ++g; }
        b += al;
      }
      meta[0] = g;
    }
    __syncthreads();
    for (int t = tid; t < T_TOK; t += 256) {
      #pragma unroll
      for (int s = 0; s < 2; ++s) {
        int e = idx2[2 * t + s];
        int p = s_base[e] + atomicAdd(&s_cur[e], 1);
        ptok[p] = t;
        pscale[p] = scale2[2 * t + s];
      }
    }
  }
  grid.sync();

  // ---- P2: astage: Ag[p][D] = bf16(scale * x[tok]); 320 units x 8 rows
  for (int u = bid; u < P_CAP / 8; u += GRID_B) {
    const int row = u * 8 + (tid >> 5);
    const int c0  = (tid & 31) * 4;
    const int   tok = ptok[row];
    const float sc  = pscale[row];
    const float* xr = x + (size_t)(tok < 0 ? 0 : tok) * D_DIM;
    short* orow = Ag + (size_t)row * D_DIM;
    #pragma unroll
    for (int j = 0; j < 8; ++j) {
      int c = c0 + j * 128;
      float4_t v = *(const float4_t*)(xr + c);
      uint2_t uu = { pkbf(v[0] * sc, v[1] * sc), pkbf(v[2] * sc, v[3] * sc) };
      *(uint2_t*)(orow + c) = uu;
    }
  }
  const int nmt = meta[0];
  grid.sync();

  const int lane = tid & 63, wid = tid >> 6;
  const int wm = wid >> 1, wn = wid & 1;
  const int l31 = lane & 31, lh = lane >> 5;
  const int sr = tid >> 3, su = (tid & 7) * 8;

  // ---- P3: gemm1 tiles (<= 320): h = silu(A@w1e) * (A@w3e); 64m x 64n
  for (int u = bid; u < 8 * nmt; u += GRID_B) {
    const int nt = u & 7, mt = u >> 3;
    const int e = meta[1 + mt], row0 = meta[81 + mt];
    const int n0 = nt * 64;
    const short* bsrc = w13t + (size_t)e * D_DIM * (2 * H_DIM);
    const size_t st32 = (size_t)32 * D_DIM;
    const short* apA = Ag   + (size_t)(row0 + sr) * D_DIM + su;
    const short* ap1 = bsrc + (size_t)(n0 + sr) * D_DIM + su;
    const short* ap3 = bsrc + (size_t)(H_DIM + n0 + sr) * D_DIM + su;

    f32x16 acc1, acc3;
    #pragma unroll
    for (int i = 0; i < 16; ++i) { acc1[i] = 0.f; acc3[i] = 0.f; }

    {                                      // prologue: stage tile 0
      uint4_t a0 = *(const uint4_t*)apA;
      uint4_t a1 = *(const uint4_t*)(apA + st32);
      uint4_t p0 = *(const uint4_t*)ap1;
      uint4_t p1 = *(const uint4_t*)(ap1 + st32);
      uint4_t q0 = *(const uint4_t*)ap3;
      uint4_t q1 = *(const uint4_t*)(ap3 + st32);
      *(uint4_t*)&sh.g1.A[0][sr * LDA + su]         = a0;
      *(uint4_t*)&sh.g1.A[0][(sr + 32) * LDA + su]  = a1;
      *(uint4_t*)&sh.g1.B1[0][sr * LDA + su]        = p0;
      *(uint4_t*)&sh.g1.B1[0][(sr + 32) * LDA + su] = p1;
      *(uint4_t*)&sh.g1.B3[0][sr * LDA + su]        = q0;
      *(uint4_t*)&sh.g1.B3[0][(sr + 32) * LDA + su] = q1;
    }
    for (int t = 0; t < NK1 - 1; ++t) {
      __syncthreads();
      const int cur = t & 1, nxt = cur ^ 1;
      const int ko = (t + 1) * 64;
      uint4_t a0 = *(const uint4_t*)(apA + ko);
      uint4_t a1 = *(const uint4_t*)(apA + st32 + ko);
      uint4_t p0 = *(const uint4_t*)(ap1 + ko);
      uint4_t p1 = *(const uint4_t*)(ap1 + st32 + ko);
      uint4_t q0 = *(const uint4_t*)(ap3 + ko);
      uint4_t q1 = *(const uint4_t*)(ap3 + st32 + ko);
      short8_t af[4], b1f[4], b3f[4];
      #pragma unroll
      for (int s = 0; s < 4; ++s) {
        const int kof = s * 16 + lh * 8;
        af[s]  = *(const short8_t*)&sh.g1.A[cur][(wm * 32 + l31) * LDA + kof];
        b1f[s] = *(const short8_t*)&sh.g1.B1[cur][(wn * 32 + l31) * LDA + kof];
        b3f[s] = *(const short8_t*)&sh.g1.B3[cur][(wn * 32 + l31) * LDA + kof];
      }
      #pragma unroll
      for (int s = 0; s < 4; ++s) {
        acc1 = __builtin_amdgcn_mfma_f32_32x32x16_bf16(af[s], b1f[s], acc1, 0, 0, 0);
        acc3 = __builtin_amdgcn_mfma_f32_32x32x16_bf16(af[s], b3f[s], acc3, 0, 0, 0);
      }
      *(uint4_t*)&sh.g1.A[nxt][sr * LDA + su]         = a0;
      *(uint4_t*)&sh.g1.A[nxt][(sr + 32) * LDA + su]  = a1;
      *(uint4_t*)&sh.g1.B1[nxt][sr * LDA + su]        = p0;
      *(uint4_t*)&sh.g1.B1[nxt][(sr + 32) * LDA + su] = p1;
      *(uint4_t*)&sh.g1.B3[nxt][sr * LDA + su]        = q0;
      *(uint4_t*)&sh.g1.B3[nxt][(sr + 32) * LDA + su] = q1;
    }
    __syncthreads();
    {
      short8_t af[4], b1f[4], b3f[4];
      #pragma unroll
      for (int s = 0; s < 4; ++s) {
        const int kof = s * 16 + lh * 8;
        af[s]  = *(const short8_t*)&sh.g1.A[1][(wm * 32 + l31) * LDA + kof];
        b1f[s] = *(const short8_t*)&sh.g1.B1[1][(wn * 32 + l31) * LDA + kof];
        b3f[s] = *(const short8_t*)&sh.g1.B3[1][(wn * 32 + l31) * LDA + kof];
      }
      #pragma unroll
      for (int s = 0; s < 4; ++s) {
        acc1 = __builtin_amdgcn_mfma_f32_32x32x16_bf16(af[s], b1f[s], acc1, 0, 0, 0);
        acc3 = __builtin_amdgcn_mfma_f32_32x32x16_bf16(af[s], b3f[s], acc3, 0, 0, 0);
      }
    }
    __syncthreads();                        // LDS safe for next tile / phase
    {
      const int col = n0 + wn * 32 + l31;
      #pragma unroll
      for (int r = 0; r < 16; ++r) {
        int mrow = (r & 3) + 8 * (r >> 2) + 4 * lh;
        int grow = row0 + wm * 32 + mrow;
        float c1 = acc1[r], c3 = acc3[r];
        float sig = 1.f / (1.f + __expf(-c1));
        h[(size_t)grow * H_DIM + col] = f2bf(c1 * sig * c3);
      }
    }
  }
  grid.sync();

  // ---- P4: gemm2 tiles (<= 320): out[tok] += h @ w2t[e]; 64m x 128n
  for (int u = bid; u < 8 * nmt; u += GRID_B) {
    const int nt = u & 7, mt = u >> 3;
    const int e = meta[1 + mt], row0 = meta[81 + mt];
    const int n0 = nt * 128;
    const short* bsrc = w2t + (size_t)e * D_DIM * H_DIM;
    const size_t st32 = (size_t)32 * H_DIM;
    const short* apA = h    + (size_t)(row0 + sr) * H_DIM + su;
    const short* apB = bsrc + (size_t)(n0 + sr) * H_DIM + su;

    f32x16 accA, accB;
    #pragma unroll
    for (int i = 0; i < 16; ++i) { accA[i] = 0.f; accB[i] = 0.f; }

    {                                      // prologue: stage tile 0
      uint4_t a0 = *(const uint4_t*)apA;
      uint4_t a1 = *(const uint4_t*)(apA + st32);
      uint4_t b0 = *(const uint4_t*)apB;
      uint4_t b1 = *(const uint4_t*)(apB + st32);
      uint4_t b2 = *(const uint4_t*)(apB + 2 * st32);
      uint4_t b3 = *(const uint4_t*)(apB + 3 * st32);
      *(uint4_t*)&sh.g2.A[0][sr * LDA + su]        = a0;
      *(uint4_t*)&sh.g2.A[0][(sr + 32) * LDA + su] = a1;
      *(uint4_t*)&sh.g2.B[0][sr * LDA + su]        = b0;
      *(uint4_t*)&sh.g2.B[0][(sr + 32) * LDA + su] = b1;
      *(uint4_t*)&sh.g2.B[0][(sr + 64) * LDA + su] = b2;
      *(uint4_t*)&sh.g2.B[0][(sr + 96) * LDA + su] = b3;
    }
    for (int t = 0; t < NK2 - 1; ++t) {
      __syncthreads();
      const int cur = t & 1, nxt = cur ^ 1;
      const int ko = (t + 1) * 64;
      uint4_t a0 = *(const uint4_t*)(apA + ko);
      uint4_t a1 = *(const uint4_t*)(apA + st32 + ko);
      uint4_t b0 = *(const uint4_t*)(apB + ko);
      uint4_t b1 = *(const uint4_t*)(apB + st32 + ko);
      uint4_t b2 = *(const uint4_t*)(apB + 2 * st32 + ko);
      uint4_t b3 = *(const uint4_t*)(apB + 3 * st32 + ko);
      short8_t af[4], bf0[4], bf1[4];
      #pragma unroll
      for (int s = 0; s < 4; ++s) {
        const int kof = s * 16 + lh * 8;
        af[s]  = *(const short8_t*)&sh.g2.A[cur][(wm * 32 + l31) * LDA + kof];
        bf0[s] = *(const short8_t*)&sh.g2.B[cur][(wn * 64 + l31) * LDA + kof];
        bf1[s] = *(const short8_t*)&sh.g2.B[cur][(wn * 64 + 32 + l31) * LDA + kof];
      }
      #pragma unroll
      for (int s = 0; s < 4; ++s) {
        accA = __builtin_amdgcn_mfma_f32_32x32x16_bf16(af[s], bf0[s], accA, 0, 0, 0);
        accB = __builtin_amdgcn_mfma_f32_32x32x16_bf16(af[s], bf1[s], accB, 0, 0, 0);
      }
      *(uint4_t*)&sh.g2.A[nxt][sr * LDA + su]        = a0;
      *(uint4_t*)&sh.g2.A[nxt][(sr + 32) * LDA + su] = a1;
      *(uint4_t*)&sh.g2.B[nxt][sr * LDA + su]        = b0;
      *(uint4_t*)&sh.g2.B[nxt][(sr + 32) * LDA + su] = b1;
      *(uint4_t*)&sh.g2.B[nxt][(sr + 64) * LDA + su] = b2;
      *(uint4_t*)&sh.g2.B[nxt][(sr + 96) * LDA + su] = b3;
    }
    __syncthreads();
    {
      short8_t af[4], bf0[4], bf1[4];
      #pragma unroll
      for (int s = 0; s < 4; ++s) {
        const int kof = s * 16 + lh * 8;
        af[s]  = *(const short8_t*)&sh.g2.A[1][(wm * 32 + l31) * LDA + kof];
        bf0[s] = *(const short8_t*)&sh.g2.B[1][(wn * 64 + l31) * LDA + kof];
        bf1[s] = *(const short8_t*)&sh.g2.B[1][(wn * 64 + 32 + l31) * LDA + kof];
      }
      #pragma unroll
      for (int s = 0; s < 4; ++s) {
        accA = __builtin_amdgcn_mfma_f32_32x32x16_bf16(af[s], bf0[s], accA, 0, 0, 0);
        accB = __builtin_amdgcn_mfma_f32_32x32x16_bf16(af[s], bf1[s], accB, 0, 0, 0);
      }
    }
    __syncthreads();                        // LDS safe for next tile
    {
      #pragma unroll
      for (int r = 0; r < 16; ++r) {
        int mrow = (r & 3) + 8 * (r >> 2) + 4 * lh;
        int grow = row0 + wm * 32 + mrow;
        int tok = ptok[grow];
        if (tok < 0) continue;
        float* orow = out + (size_t)tok * D_DIM;
        atomicAdd(orow + n0 + wn * 64 + l31, accA[r]);
        atomicAdd(orow + n0 + wn * 64 + 32 + l31, accB[r]);
      }
    }
  }
}

// ================= fallback path: proven 5-kernel pipeline =================
__global__ __launch_bounds__(256) void prep_kernel(
    const float* __restrict__ w1, const float* __restrict__ w3,
    const float* __restrict__ w2, const float* __restrict__ x,
    const float* __restrict__ gw, short* __restrict__ w13t,
    short* __restrict__ w2t, int* __restrict__ idx2,
    float* __restrict__ scale2, float* __restrict__ out) {
  __shared__ float tile[64 * 69];
  const int z = blockIdx.z;
  const int tid = threadIdx.x;
  if (z < 24) {
    const float* src; short* dst; int N, ldd, row_off, k0, n0;
    if (z < 16) {
      if (blockIdx.y >= 8) return;
      int which = z >> 3, e = z & 7;
      src = (which ? w3 : w1) + (size_t)e * D_DIM * H_DIM;
      dst = w13t + (size_t)e * D_DIM * (2 * H_DIM);
      N = H_DIM; ldd = D_DIM; row_off = which ? H_DIM : 0;
    } else {
      if (blockIdx.x >= 8) return;
      int e = z - 16;
      src = w2 + (size_t)e * H_DIM * D_DIM;
      dst = w2t + (size_t)e * D_DIM * H_DIM;
      N = D_DIM; ldd = H_DIM; row_off = 0;
    }
    k0 = blockIdx.x * 64; n0 = blockIdx.y * 64;
    transpose_tile(src, dst, N, ldd, row_off, k0, n0, tid, tile);
    return;
  }
  if (z == 25) {
    float4_t z4 = {0.f, 0.f, 0.f, 0.f};
    float4_t* o = (float4_t*)(out + ((size_t)(blockIdx.y * 16 + blockIdx.x)) * 4096);
    #pragma unroll
    for (int i = 0; i < 4; ++i) o[i * 256 + tid] = z4;
    return;
  }
  router4(blockIdx.y * 16 + blockIdx.x, x, gw, idx2, scale2, tid);
}

__global__ __launch_bounds__(256) void scan_kernel(
    const int* __restrict__ idx2, const float* __restrict__ scale2,
    int* __restrict__ pair_tok, float* __restrict__ pair_scale,
    int* __restrict__ meta) {
  __shared__ int cnt[E_EXP], base[E_EXP], cur[E_EXP];
  const int tid = threadIdx.x;
  if (tid < E_EXP) { cnt[tid] = 0; cur[tid] = 0; }
  for (int p = tid; p < P_CAP; p += 256) { pair_tok[p] = -1; pair_scale[p] = 0.f; }
  __syncthreads();
  for (int t = tid; t < T_TOK; t += 256) {
    atomicAdd(&cnt[idx2[2 * t]], 1);
    atomicAdd(&cnt[idx2[2 * t + 1]], 1);
  }
  __syncthreads();
  if (tid == 0) {
    int b = 0, g = 0;
    for (int e = 0; e < E_EXP; ++e) {
      base[e] = b;
      int al = (cnt[e] + 63) & ~63;
      for (int j = 0; j < al; j += 64) { meta[1 + g] = e; meta[81 + g] = b + j; ++g; }
      b += al;
    }
    meta[0] = g;
  }
  __syncthreads();
  for (int t = tid; t < T_TOK; t += 256) {
    #pragma unroll
    for (int s = 0; s < 2; ++s) {
      int e = idx2[2 * t + s];
      int p = base[e] + atomicAdd(&cur[e], 1);
      pair_tok[p] = t;
      pair_scale[p] = scale2[2 * t + s];
    }
  }
}

__global__ __launch_bounds__(256) void astage_kernel(
    const float* __restrict__ x, const int* __restrict__ pair_tok,
    const float* __restrict__ pair_scale, short* __restrict__ Ag) {
  const int tid = threadIdx.x;
  const int row = blockIdx.x * 8 + (tid >> 5);
  const int c0  = (tid & 31) * 4;
  const int   tok = pair_tok[row];
  const float sc  = pair_scale[row];
  const float* xr = x + (size_t)(tok < 0 ? 0 : tok) * D_DIM;
  short* orow = Ag + (size_t)row * D_DIM;
  #pragma unroll
  for (int j = 0; j < 8; ++j) {
    int c = c0 + j * 128;
    float4_t v = *(const float4_t*)(xr + c);
    uint2_t u = { pkbf(v[0] * sc, v[1] * sc), pkbf(v[2] * sc, v[3] * sc) };
    *(uint2_t*)(orow + c) = u;
  }
}

__global__ __launch_bounds__(256, 2) void gemm1_kernel(
    const short* __restrict__ Ag, const short* __restrict__ w13t,
    const int* __restrict__ meta, short* __restrict__ h) {
  __shared__ SharedU sh;
  const int mt = blockIdx.y;
  if (mt >= meta[0]) return;
  const int e = meta[1 + mt], row0 = meta[81 + mt];
  const int n0 = blockIdx.x * 64;
  const int tid = threadIdx.x, lane = tid & 63, wid = tid >> 6;
  const int wm = wid >> 1, wn = wid & 1;
  const int l31 = lane & 31, lh = lane >> 5;
  const int sr = tid >> 3, su = (tid & 7) * 8;
  const short* bsrc = w13t + (size_t)e * D_DIM * (2 * H_DIM);
  const size_t st32 = (size_t)32 * D_DIM;
  const short* apA = Ag   + (size_t)(row0 + sr) * D_DIM + su;
  const short* ap1 = bsrc + (size_t)(n0 + sr) * D_DIM + su;
  const short* ap3 = bsrc + (size_t)(H_DIM + n0 + sr) * D_DIM + su;
  f32x16 acc1, acc3;
  #pragma unroll
  for (int i = 0; i < 16; ++i) { acc1[i] = 0.f; acc3[i] = 0.f; }
  {
    *(uint4_t*)&sh.g1.A[0][sr * LDA + su]         = *(const uint4_t*)apA;
    *(uint4_t*)&sh.g1.A[0][(sr + 32) * LDA + su]  = *(const uint4_t*)(apA + st32);
    *(uint4_t*)&sh.g1.B1[0][sr * LDA + su]        = *(const uint4_t*)ap1;
    *(uint4_t*)&sh.g1.B1[0][(sr + 32) * LDA + su] = *(const uint4_t*)(ap1 + st32);
    *(uint4_t*)&sh.g1.B3[0][sr * LDA + su]        = *(const uint4_t*)ap3;
    *(uint4_t*)&sh.g1.B3[0][(sr + 32) * LDA + su] = *(const uint4_t*)(ap3 + st32);
  }
  for (int t = 0; t < NK1 - 1; ++t) {
    __syncthreads();
    const int cur = t & 1, nxt = cur ^ 1;
    const int ko = (t + 1) * 64;
    uint4_t a0 = *(const uint4_t*)(apA + ko);
    uint4_t a1 = *(const uint4_t*)(apA + st32 + ko);
    uint4_t p0 = *(const uint4_t*)(ap1 + ko);
    uint4_t p1 = *(const uint4_t*)(ap1 + st32 + ko);
    uint4_t q0 = *(const uint4_t*)(ap3 + ko);
    uint4_t q1 = *(const uint4_t*)(ap3 + st32 + ko);
    short8_t af[4], b1f[4], b3f[4];
    #pragma unroll
    for (int s = 0; s < 4; ++s) {
      const int kof = s * 16 + lh * 8;
      af[s]  = *(const short8_t*)&sh.g1.A[cur][(wm * 32 + l31) * LDA + kof];
      b1f[s] = *(const short8_t*)&sh.g1.B1[cur][(wn * 32 + l31) * LDA + kof];
      b3f[s] = *(const short8_t*)&sh.g1.B3[cur][(wn * 32 + l31) * LDA + kof];
    }
    #pragma unroll
    for (int s = 0; s < 4; ++s) {
      acc1 = __builtin_amdgcn_mfma_f32_32x32x16_bf16(af[s], b1f[s], acc1, 0, 0, 0);
      acc3 = __builtin_amdgcn_mfma_f32_32x32x16_bf16(af[s], b3f[s], acc3, 0, 0, 0);
    }
    *(uint4_t*)&sh.g1.A[nxt][sr * LDA + su]         = a0;
    *(uint4_t*)&sh.g1.A[nxt][(sr + 32) * LDA + su]  = a1;
    *(uint4_t*)&sh.g1.B1[nxt][sr * LDA + su]        = p0;
    *(uint4_t*)&sh.g1.B1[nxt][(sr + 32) * LDA + su] = p1;
    *(uint4_t*)&sh.g1.B3[nxt][sr * LDA + su]        = q0;
    *(uint4_t*)&sh.g1.B3[nxt][(sr + 32) * LDA + su] = q1;
  }
  __syncthreads();
  {
    short8_t af[4], b1f[4], b3f[4];
    #pragma unroll
    for (int s = 0; s < 4; ++s) {
      const int kof = s * 16 + lh * 8;
      af[s]  = *(const short8_t*)&sh.g1.A[1][(wm * 32 + l31) * LDA + kof];
      b1f[s] = *(const short8_t*)&sh.g1.B1[1][(wn * 32 + l31) * LDA + kof];
      b3f[s] = *(const short8_t*)&sh.g1.B3[1][(wn * 32 + l31) * LDA + kof];
    }
    #pragma unroll
    for (int s = 0; s < 4; ++s) {
      acc1 = __builtin_amdgcn_mfma_f32_32x32x16_bf16(af[s], b1f[s], acc1, 0, 0, 0);
      acc3 = __builtin_amdgcn_mfma_f32_32x32x16_bf16(af[s], b3f[s], acc3, 0, 0, 0);
    }
  }
  {
    const int col = n0 + wn * 32 + l31;
    #pragma unroll
    for (int r = 0; r < 16; ++r) {
      int mrow = (r & 3) + 8 * (r >> 2) + 4 * lh;
      int grow = row0 + wm * 32 + mrow;
      float c1 = acc1[r], c3 = acc3[r];
      float sig = 1.f / (1.f + __expf(-c1));
      h[(size_t)grow * H_DIM + col] = f2bf(c1 * sig * c3);
    }
  }
}

__global__ __launch_bounds__(256, 2) void gemm2_kernel(
    const short* __restrict__ h, const short* __restrict__ w2t,
    const int* __restrict__ pair_tok, const int* __restrict__ meta,
    float* __restrict__ out) {
  __shared__ SharedU sh;
  const int mt = blockIdx.y;
  if (mt >= meta[0]) return;
  const int e = meta[1 + mt], row0 = meta[81 + mt];
  const int n0 = blockIdx.x * 128;
  const int tid = threadIdx.x, lane = tid & 63, wid = tid >> 6;
  const int wm = wid >> 1, wn = wid & 1;
  const int l31 = lane & 31, lh = lane >> 5;
  const int sr = tid >> 3, su = (tid & 7) * 8;
  const short* bsrc = w2t + (size_t)e * D_DIM * H_DIM;
  const size_t st32 = (size_t)32 * H_DIM;
  const short* apA = h    + (size_t)(row0 + sr) * H_DIM + su;
  const short* apB = bsrc + (size_t)(n0 + sr) * H_DIM + su;
  f32x16 accA, accB;
  #pragma unroll
  for (int i = 0; i < 16; ++i) { accA[i] = 0.f; accB[i] = 0.f; }
  {
    *(uint4_t*)&sh.g2.A[0][sr * LDA + su]        = *(const uint4_t*)apA;
    *(uint4_t*)&sh.g2.A[0][(sr + 32) * LDA + su] = *(const uint4_t*)(apA + st32);
    *(uint4_t*)&sh.g2.B[0][sr * LDA + su]        = *(const uint4_t*)apB;
    *(uint4_t*)&sh.g2.B[0][(sr + 32) * LDA + su] = *(const uint4_t*)(apB + st32);
    *(uint4_t*)&sh.g2.B[0][(sr + 64) * LDA + su] = *(const uint4_t*)(apB + 2 * st32);
    *(uint4_t*)&sh.g2.B[0][(sr + 96) * LDA + su] = *(const uint4_t*)(apB + 3 * st32);
  }
  for (int t = 0; t < NK2 - 1; ++t) {
    __syncthreads();
    const int cur = t & 1, nxt = cur ^ 1;
    const int ko = (t + 1) * 64;
    uint4_t a0 = *(const uint4_t*)(apA + ko);
    uint4_t a1 = *(const uint4_t*)(apA + st32 + ko);
    uint4_t b0 = *(const uint4_t*)(apB + ko);
    uint4_t b1 = *(const uint4_t*)(apB + st32 + ko);
    uint4_t b2 = *(const uint4_t*)(apB + 2 * st32 + ko);
    uint4_t b3 = *(const uint4_t*)(apB + 3 * st32 + ko);
    short8_t af[4], bf0[4], bf1[4];
    #pragma unroll
    for (int s = 0; s < 4; ++s) {
      const int kof = s * 16 + lh * 8;
      af[s]  = *(const short8_t*)&sh.g2.A[cur][(wm * 32 + l31) * LDA + kof];
      bf0[s] = *(const short8_t*)&sh.g2.B[cur][(wn * 64 + l31) * LDA + kof];
      bf1[s] = *(const short8_t*)&sh.g2.B[cur][(wn * 64 + 32 + l31) * LDA + kof];
    }
    #pragma unroll
    for (int s = 0; s < 4; ++s) {
      accA = __builtin_amdgcn_mfma_f32_32x32x16_bf16(af[s], bf0[s], accA, 0, 0, 0);
      accB = __builtin_amdgcn_mfma_f32_32x32x16_bf16(af[s], bf1[s], accB, 0, 0, 0);
    }
    *(uint4_t*)&sh.g2.A[nxt][sr * LDA + su]        = a0;
    *(uint4_t*)&sh.g2.A[nxt][(sr + 32) * LDA + su] = a1;
    *(uint4_t*)&sh.g2.B[nxt][sr * LDA + su]        = b0;
    *(uint4_t*)&sh.g2.B[nxt][(sr + 32) * LDA + su] = b1;
    *(uint4_t*)&sh.g2.B[nxt][(sr + 64) * LDA + su] = b2;
    *(uint4_t*)&sh.g2.B[nxt][(sr + 96) * LDA + su] = b3;
  }
  __syncthreads();
  {
    short8_t af[4], bf0[4], bf1[4];
    #pragma unroll
    for (int s = 0; s < 4; ++s) {
      const int kof = s * 16 + lh * 8;
      af[s]  = *(const short8_t*)&sh.g2.A[1][(wm * 32 + l31) * LDA + kof];
      bf0[s] = *(const short8_t*)&sh.g2.B[1][(wn * 64 + l31) * LDA + kof];
      bf1[s] = *(const short8_t*)&sh.g2.B[1][(wn * 64 + 32 + l31) * LDA + kof];
    }
    #pragma unroll
    for (int s = 0; s < 4; ++s) {
      accA = __builtin_amdgcn_mfma_f32_32x32x16_bf16(af[s], bf0[s], accA, 0, 0, 0);
      accB = __builtin_amdgcn_mfma_f32_32x32x16_bf16(af[s], bf1[s], accB, 0, 0, 0);
    }
  }
  {
    #pragma unroll
    for (int r = 0; r < 16; ++r) {
      int mrow = (r & 3) + 8 * (r >> 2) + 4 * lh;
      int grow = row0 + wm * 32 + mrow;
      int tok = pair_tok[grow];
      if (tok < 0) continue;
      float* orow = out + (size_t)tok * D_DIM;
      atomicAdd(orow + n0 + wn * 64 + l31, accA[r]);
      atomicAdd(orow + n0 + wn * 64 + 32 + l31, accB[r]);
    }
  }
}

extern "C" void kernel_launch(void* const* d_in, const int* in_sizes, int n_in,
                              void* d_out, int out_size, void* d_ws, size_t ws_size,
                              hipStream_t stream) {
  const float* x  = (const float*)d_in[0];   // [2,512,1024]
  const float* gw = (const float*)d_in[1];   // [1024,8]
  const float* w1 = (const float*)d_in[2];   // [8,1024,512] gate
  const float* w2 = (const float*)d_in[3];   // [8,512,1024] down
  const float* w3 = (const float*)d_in[4];   // [8,1024,512] up
  float* out = (float*)d_out;

  char* ws = (char*)d_ws;
  int*   idx2    = (int*)  (ws);                       // 8KB
  float* scale2  = (float*)(ws + 8192);                // 8KB
  int*   ptok    = (int*)  (ws + 16384);               // 10KB (16KB slot)
  float* pscale  = (float*)(ws + 32768);               // 10KB (16KB slot)
  int*   meta    = (int*)  (ws + 49152);               // 640B (16KB slot)
  short* h       = (short*)(ws + (1u << 20));          // 2.62 MB
  short* w13t    = (short*)(ws + (4u << 20));          // 16.8 MB
  short* w2t     = (short*)(ws + (21u << 20));         // 8.4 MB
  short* Ag      = (short*)(ws + (30u << 20));         // 5.24 MB scaled-bf16 A

  void* kargs[] = {(void*)&x, (void*)&gw, (void*)&w1, (void*)&w2, (void*)&w3,
                   (void*)&w13t, (void*)&w2t, (void*)&idx2, (void*)&scale2,
                   (void*)&ptok, (void*)&pscale, (void*)&meta, (void*)&Ag,
                   (void*)&h, (void*)&out};
  hipError_t err = hipLaunchCooperativeKernel(
      (const void*)moe_fused, dim3(GRID_B), dim3(256), kargs, 0, stream);
  if (err != hipSuccess) {
    // fallback: proven 5-kernel pipeline (R2-equivalent)
    prep_kernel<<<dim3(16, 16, 26), dim3(256), 0, stream>>>(
        w1, w3, w2, x, gw, w13t, w2t, idx2, scale2, out);
    scan_kernel<<<dim3(1), dim3(256), 0, stream>>>(idx2, scale2, ptok, pscale, meta);
    astage_kernel<<<dim3(P_CAP / 8), dim3(256), 0, stream>>>(x, ptok, pscale, Ag);
    gemm1_kernel<<<dim3(H_DIM / 64, MAX_MT), dim3(256), 0, stream>>>(
        Ag, w13t, meta, h);
    gemm2_kernel<<<dim3(D_DIM / 128, MAX_MT), dim3(256), 0, stream>>>(
        h, w2t, ptok, meta, out);
  }
}

// Round 4
// 146.501 us; speedup vs baseline: 2.6842x; 2.6842x over previous
//
#include <hip/hip_runtime.h>
#include <hip/hip_bf16.h>
#include <cstddef>

#define T_TOK 1024
#define D_DIM 1024
#define H_DIM 512
#define E_EXP 8
#define P_CAP 2560          // max padded pairs @64-align: 2048 + 8*63 = 2552 -> 2560
#define MAX_MT 40           // 64-row m-tiles
#define LDA 72              // shorts per LDS row: 64 data + 8 pad (144B, 16B-aligned)
#define NK1 16              // gemm1 K-steps: 1024/64
#define NK2 8               // gemm2 K-steps: 512/64

typedef __attribute__((ext_vector_type(4)))  float    float4_t;
typedef __attribute__((ext_vector_type(16))) float    f32x16;
typedef __attribute__((ext_vector_type(8)))  short    short8_t;
typedef __attribute__((ext_vector_type(4)))  unsigned uint4_t;

__device__ __forceinline__ short f2bf(float f) {
  union { float f; unsigned u; } v; v.f = f;
  unsigned u = v.u;
  u += 0x7FFFu + ((u >> 16) & 1u);
  return (short)(u >> 16);
}

// packed fp32x2 -> bf16x2; low short = a, high = b
__device__ __forceinline__ unsigned pkbf(float a, float b) {
  union { __hip_bfloat162 h; unsigned u; } v;
  v.h = __float22bfloat162_rn(make_float2(a, b));
  return v.u;
}

// ---- prep: weight transpose+convert (z<24) + router (z==24) + out=0 (z==25)
// tile stride 69 floats (odd) keeps transpose reads <=2-way.
__global__ __launch_bounds__(256) void prep_kernel(
    const float* __restrict__ w1, const float* __restrict__ w3,
    const float* __restrict__ w2, const float* __restrict__ x,
    const float* __restrict__ gw, short* __restrict__ w13t,
    short* __restrict__ w2t, int* __restrict__ idx2,
    float* __restrict__ scale2, float* __restrict__ out) {
  __shared__ float tile[64][69];
  const int z = blockIdx.z;
  const int tid = threadIdx.x;

  if (z < 24) {
    const float* src; short* dst; int N, ldd, row_off;
    if (z < 16) {
      if (blockIdx.y >= 8) return;          // N=512 -> 8 n-tiles
      int which = z >> 3, e = z & 7;
      src = (which ? w3 : w1) + (size_t)e * D_DIM * H_DIM;
      dst = w13t + (size_t)e * D_DIM * (2 * H_DIM);
      N = H_DIM; ldd = D_DIM; row_off = which ? H_DIM : 0;
    } else {
      if (blockIdx.x >= 8) return;          // K=512 -> 8 k-tiles
      int e = z - 16;
      src = w2 + (size_t)e * H_DIM * D_DIM;
      dst = w2t + (size_t)e * D_DIM * H_DIM;
      N = D_DIM; ldd = H_DIM; row_off = 0;
    }
    const int k0 = blockIdx.x * 64, n0 = blockIdx.y * 64;
    const int kr = tid >> 4, nc = (tid & 15) * 4;
    #pragma unroll
    for (int p = 0; p < 4; ++p) {
      int k = p * 16 + kr;
      float4_t v = *(const float4_t*)(src + (size_t)(k0 + k) * N + n0 + nc);
      tile[k][nc]     = v[0];
      tile[k][nc + 1] = v[1];
      tile[k][nc + 2] = v[2];
      tile[k][nc + 3] = v[3];
    }
    __syncthreads();
    const int r8 = tid >> 3, c8 = tid & 7;
    #pragma unroll
    for (int p = 0; p < 2; ++p) {
      int row = p * 32 + r8;
      uint4_t u;
      #pragma unroll
      for (int jj = 0; jj < 4; ++jj)
        u[jj] = pkbf(tile[c8 * 8 + 2 * jj][row], tile[c8 * 8 + 2 * jj + 1][row]);
      *(uint4_t*)(dst + (size_t)(row_off + n0 + row) * ldd + k0 + c8 * 8) = u;
    }
    return;
  }

  if (z == 25) {                            // zero out[] : 256 blocks x 16KB
    float4_t z4 = {0.f, 0.f, 0.f, 0.f};
    float4_t* o = (float4_t*)(out + ((size_t)(blockIdx.y * 16 + blockIdx.x)) * 4096);
    #pragma unroll
    for (int i = 0; i < 4; ++i) o[i * 256 + tid] = z4;
    return;
  }

  // z == 24: router, 4 tokens per block (one wave each)
  const int wid  = tid >> 6;
  const int lane = tid & 63;
  const int t = (blockIdx.y * 16 + blockIdx.x) * 4 + wid;
  const float* xr = x + (size_t)t * D_DIM;
  float acc[E_EXP];
  #pragma unroll
  for (int e = 0; e < E_EXP; ++e) acc[e] = 0.f;
  for (int d = lane; d < D_DIM; d += 64) {
    float xv = xr[d];
    float4_t g0 = *(const float4_t*)(gw + d * E_EXP);
    float4_t g1 = *(const float4_t*)(gw + d * E_EXP + 4);
    acc[0] += xv * g0[0]; acc[1] += xv * g0[1];
    acc[2] += xv * g0[2]; acc[3] += xv * g0[3];
    acc[4] += xv * g1[0]; acc[5] += xv * g1[1];
    acc[6] += xv * g1[2]; acc[7] += xv * g1[3];
  }
  #pragma unroll
  for (int off = 32; off >= 1; off >>= 1) {
    #pragma unroll
    for (int e = 0; e < E_EXP; ++e) acc[e] += __shfl_down(acc[e], off, 64);
  }
  if (lane == 0) {
    float m = acc[0];
    #pragma unroll
    for (int e = 1; e < E_EXP; ++e) m = fmaxf(m, acc[e]);
    float p[E_EXP]; float s = 0.f;
    #pragma unroll
    for (int e = 0; e < E_EXP; ++e) { p[e] = __expf(acc[e] - m); s += p[e]; }
    float inv = 1.f / s;
    #pragma unroll
    for (int e = 0; e < E_EXP; ++e) p[e] *= inv;
    int i1 = 0;
    #pragma unroll
    for (int e = 1; e < E_EXP; ++e) if (p[e] > p[i1]) i1 = e;  // jax low-index tiebreak
    int i2 = (i1 == 0) ? 1 : 0;
    #pragma unroll
    for (int e = 0; e < E_EXP; ++e) {
      if (e == i1 || e == i2) continue;
      if (p[e] > p[i2]) i2 = e;
    }
    idx2[2 * t]     = i1;  scale2[2 * t]     = p[i1];
    idx2[2 * t + 1] = i2;  scale2[2 * t + 1] = p[i2];
  }
}

// ---- scan/assign: histogram -> 64-aligned bases -> tile table -> pair lists
__global__ __launch_bounds__(256) void scan_kernel(
    const int* __restrict__ idx2, const float* __restrict__ scale2,
    int* __restrict__ pair_tok, float* __restrict__ pair_scale,
    int* __restrict__ meta) {
  __shared__ int cnt[E_EXP], base[E_EXP], cur[E_EXP];
  const int tid = threadIdx.x;
  if (tid < E_EXP) { cnt[tid] = 0; cur[tid] = 0; }
  for (int p = tid; p < P_CAP; p += 256) { pair_tok[p] = -1; pair_scale[p] = 0.f; }
  __syncthreads();
  for (int t = tid; t < T_TOK; t += 256) {
    atomicAdd(&cnt[idx2[2 * t]], 1);
    atomicAdd(&cnt[idx2[2 * t + 1]], 1);
  }
  __syncthreads();
  if (tid == 0) {
    int b = 0, g = 0;
    for (int e = 0; e < E_EXP; ++e) {
      base[e] = b;
      int al = (cnt[e] + 63) & ~63;       // 64-row tiles
      for (int j = 0; j < al; j += 64) { meta[1 + g] = e; meta[81 + g] = b + j; ++g; }
      b += al;
    }
    meta[0] = g;  // n_mtiles (<= 40)
  }
  __syncthreads();
  for (int t = tid; t < T_TOK; t += 256) {
    #pragma unroll
    for (int s = 0; s < 2; ++s) {
      int e = idx2[2 * t + s];
      int p = base[e] + atomicAdd(&cur[e], 1);
      pair_tok[p] = t;
      pair_scale[p] = scale2[2 * t + s];
    }
  }
}

// ------- gemm1: h = silu((s*x)@w1e) * ((s*x)@w3e); block 64m x 64n ---------
// A gather+scale+convert fused into staging (saves the astage launch; the
// 8x n-block redundancy is pure VALU and was measured free in R0).
// 32x32x16 MFMA; A/B frag row=lane&31, k=(lane>>5)*8+j; C/D col=lane&31,
// row=(reg&3)+8*(reg>>2)+4*(lane>>5)  [m74/m101 verified].
__global__ __launch_bounds__(256, 2) void gemm1_kernel(
    const float* __restrict__ x, const short* __restrict__ w13t,
    const int* __restrict__ pair_tok, const float* __restrict__ pair_scale,
    const int* __restrict__ meta, short* __restrict__ h) {
  __shared__ short As[2][64 * LDA];    // 18.4 KB
  __shared__ short B1s[2][64 * LDA];   // 18.4 KB
  __shared__ short B3s[2][64 * LDA];   // 18.4 KB -> 55.3 KB total
  const int mt = blockIdx.y;
  if (mt >= meta[0]) return;
  const int e    = meta[1 + mt];
  const int row0 = meta[81 + mt];
  const int n0   = blockIdx.x * 64;
  const int tid = threadIdx.x, lane = tid & 63, wid = tid >> 6;
  const int wm = wid >> 1, wn = wid & 1;        // 2x2 waves, each 32m x 32n
  const int l31 = lane & 31, lh = lane >> 5;
  const short* bsrc = w13t + (size_t)e * D_DIM * (2 * H_DIM);

  // staging: thread owns k-segment su of rows sr and sr+32 (A) / B rows
  const int sr = tid >> 3, su = (tid & 7) * 8;
  const size_t st32 = (size_t)32 * D_DIM;
  const int   tok0 = pair_tok[row0 + sr];
  const int   tok1 = pair_tok[row0 + sr + 32];
  const float sc0  = pair_scale[row0 + sr];       // 0 for pad rows -> zeros
  const float sc1  = pair_scale[row0 + sr + 32];
  const float* xr0 = x + (size_t)(tok0 < 0 ? 0 : tok0) * D_DIM + su;
  const float* xr1 = x + (size_t)(tok1 < 0 ? 0 : tok1) * D_DIM + su;
  const short* ap1 = bsrc + (size_t)(n0 + sr) * D_DIM + su;
  const short* ap3 = bsrc + (size_t)(H_DIM + n0 + sr) * D_DIM + su;

  f32x16 acc1, acc3;
  #pragma unroll
  for (int i = 0; i < 16; ++i) { acc1[i] = 0.f; acc3[i] = 0.f; }

  {                                            // prologue: stage tile 0
    float4_t v0 = *(const float4_t*)(xr0);
    float4_t v1 = *(const float4_t*)(xr0 + 4);
    float4_t w0 = *(const float4_t*)(xr1);
    float4_t w1v = *(const float4_t*)(xr1 + 4);
    uint4_t a0 = {pkbf(v0[0] * sc0, v0[1] * sc0), pkbf(v0[2] * sc0, v0[3] * sc0),
                  pkbf(v1[0] * sc0, v1[1] * sc0), pkbf(v1[2] * sc0, v1[3] * sc0)};
    uint4_t a1 = {pkbf(w0[0] * sc1, w0[1] * sc1), pkbf(w0[2] * sc1, w0[3] * sc1),
                  pkbf(w1v[0] * sc1, w1v[1] * sc1), pkbf(w1v[2] * sc1, w1v[3] * sc1)};
    uint4_t p0 = *(const uint4_t*)ap1;
    uint4_t p1 = *(const uint4_t*)(ap1 + st32);
    uint4_t q0 = *(const uint4_t*)ap3;
    uint4_t q1 = *(const uint4_t*)(ap3 + st32);
    *(uint4_t*)&As[0][sr * LDA + su]         = a0;
    *(uint4_t*)&As[0][(sr + 32) * LDA + su]  = a1;
    *(uint4_t*)&B1s[0][sr * LDA + su]        = p0;
    *(uint4_t*)&B1s[0][(sr + 32) * LDA + su] = p1;
    *(uint4_t*)&B3s[0][sr * LDA + su]        = q0;
    *(uint4_t*)&B3s[0][(sr + 32) * LDA + su] = q1;
  }

  for (int t = 0; t < NK1 - 1; ++t) {
    __syncthreads();
    const int cur = t & 1, nxt = cur ^ 1;
    const int ko = (t + 1) * 64;
    float4_t v0 = *(const float4_t*)(xr0 + ko);
    float4_t v1 = *(const float4_t*)(xr0 + ko + 4);
    float4_t w0 = *(const float4_t*)(xr1 + ko);
    float4_t w1v = *(const float4_t*)(xr1 + ko + 4);
    uint4_t p0 = *(const uint4_t*)(ap1 + ko);
    uint4_t p1 = *(const uint4_t*)(ap1 + st32 + ko);
    uint4_t q0 = *(const uint4_t*)(ap3 + ko);
    uint4_t q1 = *(const uint4_t*)(ap3 + st32 + ko);

    short8_t af[4], b1f[4], b3f[4];
    #pragma unroll
    for (int s = 0; s < 4; ++s) {
      const int kof = s * 16 + lh * 8;
      af[s]  = *(const short8_t*)&As[cur][(wm * 32 + l31) * LDA + kof];
      b1f[s] = *(const short8_t*)&B1s[cur][(wn * 32 + l31) * LDA + kof];
      b3f[s] = *(const short8_t*)&B3s[cur][(wn * 32 + l31) * LDA + kof];
    }
    #pragma unroll
    for (int s = 0; s < 4; ++s) {
      acc1 = __builtin_amdgcn_mfma_f32_32x32x16_bf16(af[s], b1f[s], acc1, 0, 0, 0);
      acc3 = __builtin_amdgcn_mfma_f32_32x32x16_bf16(af[s], b3f[s], acc3, 0, 0, 0);
    }
    uint4_t a0 = {pkbf(v0[0] * sc0, v0[1] * sc0), pkbf(v0[2] * sc0, v0[3] * sc0),
                  pkbf(v1[0] * sc0, v1[1] * sc0), pkbf(v1[2] * sc0, v1[3] * sc0)};
    uint4_t a1 = {pkbf(w0[0] * sc1, w0[1] * sc1), pkbf(w0[2] * sc1, w0[3] * sc1),
                  pkbf(w1v[0] * sc1, w1v[1] * sc1), pkbf(w1v[2] * sc1, w1v[3] * sc1)};
    *(uint4_t*)&As[nxt][sr * LDA + su]         = a0;
    *(uint4_t*)&As[nxt][(sr + 32) * LDA + su]  = a1;
    *(uint4_t*)&B1s[nxt][sr * LDA + su]        = p0;
    *(uint4_t*)&B1s[nxt][(sr + 32) * LDA + su] = p1;
    *(uint4_t*)&B3s[nxt][sr * LDA + su]        = q0;
    *(uint4_t*)&B3s[nxt][(sr + 32) * LDA + su] = q1;
  }
  __syncthreads();                             // last tile in buf 1
  {
    short8_t af[4], b1f[4], b3f[4];
    #pragma unroll
    for (int s = 0; s < 4; ++s) {
      const int kof = s * 16 + lh * 8;
      af[s]  = *(const short8_t*)&As[1][(wm * 32 + l31) * LDA + kof];
      b1f[s] = *(const short8_t*)&B1s[1][(wn * 32 + l31) * LDA + kof];
      b3f[s] = *(const short8_t*)&B3s[1][(wn * 32 + l31) * LDA + kof];
    }
    #pragma unroll
    for (int s = 0; s < 4; ++s) {
      acc1 = __builtin_amdgcn_mfma_f32_32x32x16_bf16(af[s], b1f[s], acc1, 0, 0, 0);
      acc3 = __builtin_amdgcn_mfma_f32_32x32x16_bf16(af[s], b3f[s], acc3, 0, 0, 0);
    }
  }

  {                                            // epilogue: silu(c1)*c3 -> h
    const int col = n0 + wn * 32 + l31;
    #pragma unroll
    for (int r = 0; r < 16; ++r) {
      int mrow = (r & 3) + 8 * (r >> 2) + 4 * lh;
      int grow = row0 + wm * 32 + mrow;
      float c1 = acc1[r], c3 = acc3[r];
      float sig = 1.f / (1.f + __expf(-c1));
      h[(size_t)grow * H_DIM + col] = f2bf(c1 * sig * c3);
    }
  }
}

// -- gemm2 (fused combine): out[tok] += h @ w2t[e]; block 64m x 128n --------
// wave 32m x 64n (2 n-frags), 32x32x16 MFMA.
__global__ __launch_bounds__(256, 2) void gemm2_kernel(
    const short* __restrict__ h, const short* __restrict__ w2t,
    const int* __restrict__ pair_tok, const int* __restrict__ meta,
    float* __restrict__ out) {
  __shared__ short As[2][64 * LDA];    // 18.4 KB
  __shared__ short Bs[2][128 * LDA];   // 36.9 KB -> 55.3 KB total
  const int mt = blockIdx.y;
  if (mt >= meta[0]) return;
  const int e    = meta[1 + mt];
  const int row0 = meta[81 + mt];
  const int n0   = blockIdx.x * 128;
  const int tid = threadIdx.x, lane = tid & 63, wid = tid >> 6;
  const int wm = wid >> 1, wn = wid & 1;        // 2x2 waves, each 32m x 64n
  const int l31 = lane & 31, lh = lane >> 5;
  const short* bsrc = w2t + (size_t)e * D_DIM * H_DIM;  // [1024 n][512 k]

  const int sr = tid >> 3, su = (tid & 7) * 8;
  const size_t st32 = (size_t)32 * H_DIM;
  const short* apA = h    + (size_t)(row0 + sr) * H_DIM + su;
  const short* apB = bsrc + (size_t)(n0 + sr) * H_DIM + su;

  f32x16 accA, accB;
  #pragma unroll
  for (int i = 0; i < 16; ++i) { accA[i] = 0.f; accB[i] = 0.f; }

  {                                            // prologue: stage tile 0
    uint4_t a0 = *(const uint4_t*)apA;
    uint4_t a1 = *(const uint4_t*)(apA + st32);
    uint4_t b0 = *(const uint4_t*)apB;
    uint4_t b1 = *(const uint4_t*)(apB + st32);
    uint4_t b2 = *(const uint4_t*)(apB + 2 * st32);
    uint4_t b3 = *(const uint4_t*)(apB + 3 * st32);
    *(uint4_t*)&As[0][sr * LDA + su]        = a0;
    *(uint4_t*)&As[0][(sr + 32) * LDA + su] = a1;
    *(uint4_t*)&Bs[0][sr * LDA + su]        = b0;
    *(uint4_t*)&Bs[0][(sr + 32) * LDA + su] = b1;
    *(uint4_t*)&Bs[0][(sr + 64) * LDA + su] = b2;
    *(uint4_t*)&Bs[0][(sr + 96) * LDA + su] = b3;
  }

  for (int t = 0; t < NK2 - 1; ++t) {
    __syncthreads();
    const int cur = t & 1, nxt = cur ^ 1;
    const int ko = (t + 1) * 64;
    uint4_t a0 = *(const uint4_t*)(apA + ko);
    uint4_t a1 = *(const uint4_t*)(apA + st32 + ko);
    uint4_t b0 = *(const uint4_t*)(apB + ko);
    uint4_t b1 = *(const uint4_t*)(apB + st32 + ko);
    uint4_t b2 = *(const uint4_t*)(apB + 2 * st32 + ko);
    uint4_t b3 = *(const uint4_t*)(apB + 3 * st32 + ko);

    short8_t af[4], bf0[4], bf1[4];
    #pragma unroll
    for (int s = 0; s < 4; ++s) {
      const int kof = s * 16 + lh * 8;
      af[s]  = *(const short8_t*)&As[cur][(wm * 32 + l31) * LDA + kof];
      bf0[s] = *(const short8_t*)&Bs[cur][(wn * 64 + l31) * LDA + kof];
      bf1[s] = *(const short8_t*)&Bs[cur][(wn * 64 + 32 + l31) * LDA + kof];
    }
    #pragma unroll
    for (int s = 0; s < 4; ++s) {
      accA = __builtin_amdgcn_mfma_f32_32x32x16_bf16(af[s], bf0[s], accA, 0, 0, 0);
      accB = __builtin_amdgcn_mfma_f32_32x32x16_bf16(af[s], bf1[s], accB, 0, 0, 0);
    }
    *(uint4_t*)&As[nxt][sr * LDA + su]        = a0;
    *(uint4_t*)&As[nxt][(sr + 32) * LDA + su] = a1;
    *(uint4_t*)&Bs[nxt][sr * LDA + su]        = b0;
    *(uint4_t*)&Bs[nxt][(sr + 32) * LDA + su] = b1;
    *(uint4_t*)&Bs[nxt][(sr + 64) * LDA + su] = b2;
    *(uint4_t*)&Bs[nxt][(sr + 96) * LDA + su] = b3;
  }
  __syncthreads();                             // last tile in buf 1
  {
    short8_t af[4], bf0[4], bf1[4];
    #pragma unroll
    for (int s = 0; s < 4; ++s) {
      const int kof = s * 16 + lh * 8;
      af[s]  = *(const short8_t*)&As[1][(wm * 32 + l31) * LDA + kof];
      bf0[s] = *(const short8_t*)&Bs[1][(wn * 64 + l31) * LDA + kof];
      bf1[s] = *(const short8_t*)&Bs[1][(wn * 64 + 32 + l31) * LDA + kof];
    }
    #pragma unroll
    for (int s = 0; s < 4; ++s) {
      accA = __builtin_amdgcn_mfma_f32_32x32x16_bf16(af[s], bf0[s], accA, 0, 0, 0);
      accB = __builtin_amdgcn_mfma_f32_32x32x16_bf16(af[s], bf1[s], accB, 0, 0, 0);
    }
  }

  // ---- epilogue: scatter-add into out[tok]; skip pad rows (tok < 0)
  {
    #pragma unroll
    for (int r = 0; r < 16; ++r) {
      int mrow = (r & 3) + 8 * (r >> 2) + 4 * lh;
      int grow = row0 + wm * 32 + mrow;
      int tok = pair_tok[grow];
      if (tok < 0) continue;
      float* orow = out + (size_t)tok * D_DIM;
      atomicAdd(orow + n0 + wn * 64 + l31, accA[r]);
      atomicAdd(orow + n0 + wn * 64 + 32 + l31, accB[r]);
    }
  }
}

extern "C" void kernel_launch(void* const* d_in, const int* in_sizes, int n_in,
                              void* d_out, int out_size, void* d_ws, size_t ws_size,
                              hipStream_t stream) {
  const float* x  = (const float*)d_in[0];   // [2,512,1024]
  const float* gw = (const float*)d_in[1];   // [1024,8]
  const float* w1 = (const float*)d_in[2];   // [8,1024,512] gate
  const float* w2 = (const float*)d_in[3];   // [8,512,1024] down
  const float* w3 = (const float*)d_in[4];   // [8,1024,512] up
  float* out = (float*)d_out;

  char* ws = (char*)d_ws;
  int*   idx2    = (int*)  (ws);                       // 8KB
  float* scale2  = (float*)(ws + 8192);                // 8KB
  int*   ptok    = (int*)  (ws + 16384);               // 10KB (16KB slot)
  float* pscale  = (float*)(ws + 32768);               // 10KB (16KB slot)
  int*   meta    = (int*)  (ws + 49152);               // 640B (16KB slot)
  short* h       = (short*)(ws + (1u << 20));          // 2.62 MB
  short* w13t    = (short*)(ws + (4u << 20));          // 16.8 MB
  short* w2t     = (short*)(ws + (21u << 20));         // 8.4 MB

  prep_kernel<<<dim3(16, 16, 26), dim3(256), 0, stream>>>(
      w1, w3, w2, x, gw, w13t, w2t, idx2, scale2, out);
  scan_kernel<<<dim3(1), dim3(256), 0, stream>>>(idx2, scale2, ptok, pscale, meta);
  gemm1_kernel<<<dim3(H_DIM / 64, MAX_MT), dim3(256), 0, stream>>>(
      x, w13t, ptok, pscale, meta, h);
  gemm2_kernel<<<dim3(D_DIM / 128, MAX_MT), dim3(256), 0, stream>>>(
      h, w2t, ptok, meta, out);
}